// Round 1
// baseline (56.402 us; speedup 1.0000x reference)
//
#include <hip/hip_runtime.h>
#include <hip/hip_bf16.h>

#define BB 8
#define NN 1024
#define HH 512
#define TI 32
#define NEG 0.2f

typedef float f32x4 __attribute__((ext_vector_type(4)));
typedef short bf16x8 __attribute__((ext_vector_type(8)));
typedef unsigned int u32;

__device__ __forceinline__ unsigned short f2bf(float f) {
    union { float f; u32 u; } a; a.f = f;
    u32 u = a.u;
    u += 0x7fffu + ((u >> 16) & 1u);   // round-to-nearest-even
    return (unsigned short)(u >> 16);
}

// Kernel 1: per (batch, 32-row j-tile): s_src/s_dst dots + X^T bf16 [b][h][j]
__global__ __launch_bounds__(512) void prep_kernel(
    const float* __restrict__ x, const float* __restrict__ wsrc,
    const float* __restrict__ wdst, float* __restrict__ ssrc,
    float* __restrict__ sdst, unsigned short* __restrict__ xt)
{
    __shared__ __align__(16) unsigned short lt[TI][520]; // pad: 1040B row = 16B-aligned, bank-spread

    int bid = blockIdx.x;
    int b = bid & 7;
    int j0 = (bid >> 3) * TI;
    int t = threadIdx.x;
    int r = t >> 4;            // 0..31: row in tile
    int hb = (t & 15) * 32;    // h base: 16 threads cover 512 h

    const float* xrow = x + ((size_t)b * NN + j0 + r) * HH + hb;
    float psrc = 0.f, pdst = 0.f;
    #pragma unroll
    for (int q = 0; q < 8; ++q) {
        f32x4 v = *(const f32x4*)(xrow + q * 4);
        f32x4 a = *(const f32x4*)(wsrc + hb + q * 4);
        f32x4 d = *(const f32x4*)(wdst + hb + q * 4);
        psrc += v[0]*a[0] + v[1]*a[1] + v[2]*a[2] + v[3]*a[3];
        pdst += v[0]*d[0] + v[1]*d[1] + v[2]*d[2] + v[3]*d[3];
        u32 lo = (u32)f2bf(v[0]) | ((u32)f2bf(v[1]) << 16);
        u32 hi = (u32)f2bf(v[2]) | ((u32)f2bf(v[3]) << 16);
        *(u32*)&lt[r][hb + q*4 + 0] = lo;
        *(u32*)&lt[r][hb + q*4 + 2] = hi;
    }
    // reduce across the 16 threads of this row (consecutive lanes)
    #pragma unroll
    for (int k = 1; k < 16; k <<= 1) {
        psrc += __shfl_xor(psrc, k);
        pdst += __shfl_xor(pdst, k);
    }
    if ((t & 15) == 0) {
        ssrc[b * NN + j0 + r] = psrc;
        sdst[b * NN + j0 + r] = pdst;
    }
    __syncthreads();

    // transpose out: thread t owns h = t, writes XT[b][h][j0..j0+31] (64B contiguous)
    unsigned short v[32];
    #pragma unroll
    for (int rr = 0; rr < 32; ++rr) v[rr] = lt[rr][t];
    unsigned short* dst = xt + ((size_t)b * HH + t) * NN + j0;
    #pragma unroll
    for (int q = 0; q < 4; ++q) {
        bf16x8 pk;
        #pragma unroll
        for (int e = 0; e < 8; ++e) pk[e] = (short)v[q*8 + e];
        *(bf16x8*)(dst + q * 8) = pk;
    }
}

// Kernel 2: per (batch, 32-row i-tile): softmax(P) in LDS (bf16, XOR-swizzled),
// then out^T = XT(A, global) @ P^T(B, LDS) via mfma_16x16x32_bf16. No K-loop barriers.
__global__ __launch_bounds__(512) void gat_kernel(
    const float* __restrict__ ssrc, const float* __restrict__ sdst,
    const int* __restrict__ adj, const unsigned short* __restrict__ xt,
    const float* __restrict__ bptr, float* __restrict__ out)
{
    __shared__ __align__(16) float sd[NN];
    __shared__ float ss[TI];
    __shared__ float inv_l[TI];
    __shared__ __align__(16) unsigned short p[TI * NN]; // 64KB, swizzled: byte ^= (row&7)<<4

    int bid = blockIdx.x;
    int b = bid & 7;               // batch == bid%8 -> XCD-affine: XT[b] stays in one L2
    int i0 = (bid >> 3) * TI;
    int t = threadIdx.x;
    int lane = t & 63;
    int w = t >> 6;

    sd[t] = sdst[b * NN + t];
    sd[t + 512] = sdst[b * NN + t + 512];
    if (t < TI) ss[t] = ssrc[b * NN + i0 + t];
    __syncthreads();

    float bias = bptr[0];
    // Phase B: wave w handles rows w*4 .. w*4+3; 16 scores per lane held in regs
    #pragma unroll
    for (int rr = 0; rr < 4; ++rr) {
        int il = w * 4 + rr;
        int ig = i0 + il;
        float si = ss[il] + bias;
        const int* arow = adj + ((size_t)b * NN + ig) * NN;
        float sc[16];
        float m = -1e30f;
        #pragma unroll
        for (int it = 0; it < 4; ++it) {
            int j = it * 256 + lane * 4;
            int4 a4 = *(const int4*)(arow + j);
            f32x4 sv = *(const f32x4*)&sd[j];
            int av0 = a4.x, av1 = a4.y, av2 = a4.z, av3 = a4.w;
            float s0 = si + sv[0]; s0 = s0 > 0.f ? s0 : NEG * s0;
            float s1 = si + sv[1]; s1 = s1 > 0.f ? s1 : NEG * s1;
            float s2 = si + sv[2]; s2 = s2 > 0.f ? s2 : NEG * s2;
            float s3 = si + sv[3]; s3 = s3 > 0.f ? s3 : NEG * s3;
            sc[it*4+0] = (av0 != 0 || (j + 0) == ig) ? s0 : -1e30f;
            sc[it*4+1] = (av1 != 0 || (j + 1) == ig) ? s1 : -1e30f;
            sc[it*4+2] = (av2 != 0 || (j + 2) == ig) ? s2 : -1e30f;
            sc[it*4+3] = (av3 != 0 || (j + 3) == ig) ? s3 : -1e30f;
            m = fmaxf(m, fmaxf(fmaxf(sc[it*4+0], sc[it*4+1]), fmaxf(sc[it*4+2], sc[it*4+3])));
        }
        #pragma unroll
        for (int k = 1; k < 64; k <<= 1) m = fmaxf(m, __shfl_xor(m, k));
        float sum = 0.f;
        #pragma unroll
        for (int k = 0; k < 16; ++k) { float e = __expf(sc[k] - m); sc[k] = e; sum += e; }
        #pragma unroll
        for (int k = 1; k < 64; k <<= 1) sum += __shfl_xor(sum, k);
        if (lane == 0) inv_l[il] = 1.f / sum;
        #pragma unroll
        for (int it = 0; it < 4; ++it) {
            int j = it * 256 + lane * 4;
            u32 lo = (u32)f2bf(sc[it*4+0]) | ((u32)f2bf(sc[it*4+1]) << 16);
            u32 hi = (u32)f2bf(sc[it*4+2]) | ((u32)f2bf(sc[it*4+3]) << 16);
            int byte = ((il * NN + j) * 2) ^ ((il & 7) << 4);
            *(uint2*)((char*)p + byte) = make_uint2(lo, hi);
        }
    }
    __syncthreads();

    // Phase C: wave w owns h-range [w*64, w*64+64). M=h(64/wave), N=i(32), K=j(1024).
    int g = lane >> 4;
    int ln = lane & 15;
    const unsigned short* abase = xt + ((size_t)b * HH + w * 64 + ln) * NN + g * 8;
    f32x4 acc[4][2];
    #pragma unroll
    for (int ma = 0; ma < 4; ++ma)
        #pragma unroll
        for (int nb = 0; nb < 2; ++nb)
            acc[ma][nb] = (f32x4){0.f, 0.f, 0.f, 0.f};

    #pragma unroll 4
    for (int j0 = 0; j0 < NN; j0 += 32) {
        bf16x8 af[4], bfr[2];
        #pragma unroll
        for (int ma = 0; ma < 4; ++ma)
            af[ma] = *(const bf16x8*)(abase + (size_t)ma * 16 * NN + j0);
        #pragma unroll
        for (int nb = 0; nb < 2; ++nb) {
            int i = nb * 16 + ln;
            int byte = ((i * NN + j0 + g * 8) * 2) ^ ((i & 7) << 4);
            bfr[nb] = *(const bf16x8*)((const char*)p + byte);
        }
        #pragma unroll
        for (int ma = 0; ma < 4; ++ma)
            #pragma unroll
            for (int nb = 0; nb < 2; ++nb)
                acc[ma][nb] = __builtin_amdgcn_mfma_f32_16x16x32_bf16(af[ma], bfr[nb], acc[ma][nb], 0, 0, 0);
    }

    // epilogue: D[row=h_local][col=i_local]; lane: h = w*64+ma*16+g*4+r, i = i0+nb*16+ln
    #pragma unroll
    for (int nb = 0; nb < 2; ++nb) {
        float il_ = inv_l[nb * 16 + ln];
        int i = i0 + nb * 16 + ln;
        #pragma unroll
        for (int ma = 0; ma < 4; ++ma) {
            f32x4 v = acc[ma][nb];
            v *= il_;
            float* dst = out + ((size_t)b * NN + i) * HH + w * 64 + ma * 16 + g * 4;
            *(f32x4*)dst = v;
        }
    }
}

extern "C" void kernel_launch(void* const* d_in, const int* in_sizes, int n_in,
                              void* d_out, int out_size, void* d_ws, size_t ws_size,
                              hipStream_t stream) {
    const float* x    = (const float*)d_in[0];
    const int*   adj  = (const int*)d_in[1];
    const float* wsrc = (const float*)d_in[2];
    const float* wdst = (const float*)d_in[3];
    const float* bias = (const float*)d_in[4];
    float* out = (float*)d_out;

    float* ssrc = (float*)d_ws;                      // 8192 f32
    float* sdst = ssrc + BB * NN;                    // 8192 f32
    unsigned short* xt = (unsigned short*)(sdst + BB * NN); // 8*512*1024 bf16 = 8MB

    prep_kernel<<<dim3(BB * (NN / TI)), dim3(512), 0, stream>>>(x, wsrc, wdst, ssrc, sdst, xt);
    gat_kernel<<<dim3(BB * (NN / TI)), dim3(512), 0, stream>>>(ssrc, sdst, adj, xt, bias, out);
}